// Round 8
// baseline (294.030 us; speedup 1.0000x reference)
//
#include <hip/hip_runtime.h>

// CubePadding: x [B,6,C,H,W] fp32 -> out [B,6,C,H+2P,W+2P] fp32. Pure gather/copy.
// R9 (v11): "v7 x4 adjacent" -- one-shot threads, zero divides, batched MLP.
//   Interior: 8 threads per input row (row=idx>>3, slot k=idx&7; all pow2 math).
//     k=1..6 : groups 4k..4k+3. 4x dwordx4 loads (in cols 16k-2..16k+13, hoisted,
//              64B contiguous) -> 4x aligned NT dwordx4 stores (out cols 16k..16k+15).
//     k=0    : g=0..3, lft-edge splice (2 gathers + float2) + 3 fast loads.
//     k=7    : g=28..32 (5 groups), rgt-edge splice + 4 fast loads + float2.
//   Wave = exactly 8 rows: 48 pure-fast lanes + 8/8 slim edge lanes.
//   Halo rows: v8-verified gen_map gather blocks, FIRST in grid.
//   vs v7 (best ~54us): removes the per-group %33//132 divide chain, gives each
//   lane a 64B load burst + 64-80B store burst (4-deep MLP, no loop-carried deps
//   -- the pathology that sank v6/v9).
// Face order: 0=back(fb) 1=down(fd) 2=front(ff) 3=left(fl) 4=right(fr) 5=top(ft)

typedef float f32x4 __attribute__((ext_vector_type(4)));
typedef f32x4 f32x4_a8 __attribute__((aligned(8)));   // 8B-aligned 16B load

constexpr int P = 2, B = 4, C = 64, H = 128, W = 128;
constexpr int Ho = H + 2 * P, Wo = W + 2 * P;   // 132, 132
constexpr int NV = Wo / 4;                      // 33 groups per output row
constexpr int PLANES = B * 6 * C;               // 1536
constexpr int ROWS   = PLANES * H;              // 196,608 interior rows

constexpr int NHALO    = PLANES * 4 * NV;       // 202,752 = 792*256 exact
constexpr int BLK_HALO = NHALO / 256;           // 792 (first in grid)
constexpr int BLK_INT  = ROWS * 8 / 256;        // 6,144
constexpr int BLOCKS   = BLK_HALO + BLK_INT;    // 6,936

// ---- halo source maps (verified R0; re-verified v8/v10 absmax=0) ----
__device__ __forceinline__ void top_map(int f, int t, int w, int& sf, int& r, int& col) {
    switch (f) {
        case 0:  sf = 5; r = P - 1 - t; col = w;         break;
        case 1:  sf = 2; r = H - P + t; col = w;         break;
        case 2:  sf = 5; r = H - P + t; col = w;         break;
        case 3:  sf = 5; r = w;         col = t;         break;
        case 4:  sf = 5; r = w;         col = W - 1 - t; break;
        default: sf = 0; r = P - 1 - t; col = w;         break;
    }
}
__device__ __forceinline__ void bot_map(int f, int t, int w, int& sf, int& r, int& col) {
    switch (f) {
        case 0:  sf = 1; r = H - 1 - t; col = w;         break;
        case 1:  sf = 0; r = H - 1 - t; col = w;         break;
        case 2:  sf = 1; r = t;         col = w;         break;
        case 3:  sf = 1; r = w;         col = P - 1 - t; break;
        case 4:  sf = 1; r = w;         col = W - P + t; break;
        default: sf = 2; r = t;         col = w;         break;
    }
}
__device__ __forceinline__ void lft_map(int f, int h, int l, int& sf, int& r, int& col) {
    switch (f) {
        case 0:  sf = 4; r = h;         col = W - P + l; break;
        case 1:  sf = 3; r = H - 1 - l; col = h;         break;
        case 2:  sf = 3; r = h;         col = W - P + l; break;
        case 3:  sf = 0; r = h;         col = W - P + l; break;
        case 4:  sf = 2; r = h;         col = W - P + l; break;
        default: sf = 3; r = l;         col = h;         break;
    }
}
__device__ __forceinline__ void rgt_map(int f, int h, int rr, int& sf, int& r, int& col) {
    switch (f) {
        case 0:  sf = 3; r = h;          col = rr;        break;
        case 1:  sf = 4; r = H - P + rr; col = h;         break;
        case 2:  sf = 4; r = h;          col = rr;        break;
        case 3:  sf = 2; r = h;          col = rr;        break;
        case 4:  sf = 0; r = h;          col = rr;        break;
        default: sf = 4; r = P - 1 - rr; col = h;         break;
    }
}
__device__ __forceinline__ void gen_map(int f, int i, int j, int& sf, int& r, int& col) {
    bool in_h = (i >= P) && (i < H + P);
    bool in_w = (j >= P) && (j < W + P);
    if (in_h && in_w) {
        sf = f; r = i - P; col = j - P;
    } else if (!in_h) {
        int w = in_w ? (j - P) : (j < P ? 0 : W - 1);   // corners replicate strip edge
        if (i < P) top_map(f, i, w, sf, r, col);
        else       bot_map(f, i - H - P, w, sf, r, col);
    } else {
        if (j < P) lft_map(f, i - P, j,         sf, r, col);
        else       rgt_map(f, i - P, j - W - P, sf, r, col);
    }
}

__global__ __launch_bounds__(256) void cubepad_v11_kernel(const float* __restrict__ x,
                                                          float* __restrict__ out) {
    const int bid = blockIdx.x;
    const int tid = threadIdx.x;

    if (bid >= BLK_HALO) {
        // -------- interior rows: 8 one-shot lanes per row, pow2 math only --------
        const unsigned idx = (unsigned)(bid - BLK_HALO) * 256u + (unsigned)tid;
        const unsigned k   = idx & 7u;            // slot within row
        const unsigned row = idx >> 3;            // interior row [0, ROWS)
        const unsigned i   = row & 127u;          // face row
        const unsigned p   = row >> 7;            // plane (b*6+f)*C + c
        const int f  = (int)((p >> 6) % 6u);
        const int bC = (int)(((p >> 6) / 6u) * (6u * C) + (p & 63u));

        const float* rowp = x + ((size_t)row << 7);                  // input row base
        float* op = out + (size_t)p * (Ho * Wo) + (size_t)(i + P) * Wo;  // out row base

        if (k - 1u < 6u) {
            // slots 1..6: groups 4k..4k+3 <- in cols 16k-2 .. 16k+13
            const float* s = rowp + (k << 4) - 2u;
            const f32x4 a = *(const f32x4_a8*)(s);
            const f32x4 b = *(const f32x4_a8*)(s + 4);
            const f32x4 c = *(const f32x4_a8*)(s + 8);
            const f32x4 d = *(const f32x4_a8*)(s + 12);
            float* o = op + (k << 4);
            __builtin_nontemporal_store(a, (f32x4*)(o));
            __builtin_nontemporal_store(b, (f32x4*)(o + 4));
            __builtin_nontemporal_store(c, (f32x4*)(o + 8));
            __builtin_nontemporal_store(d, (f32x4*)(o + 12));
        } else if (k == 0u) {
            // groups 0..3: lft splice + in cols 0..13
            const float2 t = *(const float2*)(rowp);       // in 0,1
            const f32x4 a = *(const f32x4_a8*)(rowp + 2);  // in 2..5
            const f32x4 b = *(const f32x4_a8*)(rowp + 6);
            const f32x4 c = *(const f32x4_a8*)(rowp + 10);
            int sf, rr, cc;
            f32x4 e;
            lft_map(f, (int)i, 0, sf, rr, cc);
            e[0] = x[((size_t)(bC + sf * C)) * (H * W) + ((size_t)rr << 7) + cc];
            lft_map(f, (int)i, 1, sf, rr, cc);
            e[1] = x[((size_t)(bC + sf * C)) * (H * W) + ((size_t)rr << 7) + cc];
            e[2] = t.x; e[3] = t.y;
            __builtin_nontemporal_store(e, (f32x4*)(op));
            __builtin_nontemporal_store(a, (f32x4*)(op + 4));
            __builtin_nontemporal_store(b, (f32x4*)(op + 8));
            __builtin_nontemporal_store(c, (f32x4*)(op + 12));
        } else {
            // slot 7: groups 28..32 <- in cols 110..127 + rgt splice
            const float* s = rowp + 110;
            const f32x4 a = *(const f32x4_a8*)(s);          // 110..113
            const f32x4 b = *(const f32x4_a8*)(s + 4);
            const f32x4 c = *(const f32x4_a8*)(s + 8);
            const f32x4 d = *(const f32x4_a8*)(s + 12);     // 122..125
            const float2 t = *(const float2*)(rowp + 126);  // 126,127
            int sf, rr, cc;
            f32x4 e;
            rgt_map(f, (int)i, 0, sf, rr, cc);
            e[2] = x[((size_t)(bC + sf * C)) * (H * W) + ((size_t)rr << 7) + cc];
            rgt_map(f, (int)i, 1, sf, rr, cc);
            e[3] = x[((size_t)(bC + sf * C)) * (H * W) + ((size_t)rr << 7) + cc];
            e[0] = t.x; e[1] = t.y;
            float* o = op + 112;
            __builtin_nontemporal_store(a, (f32x4*)(o));
            __builtin_nontemporal_store(b, (f32x4*)(o + 4));
            __builtin_nontemporal_store(c, (f32x4*)(o + 8));
            __builtin_nontemporal_store(d, (f32x4*)(o + 12));
            __builtin_nontemporal_store(e, (f32x4*)(o + 16));
        }
        return;
    }

    // ---------------- halo rows (gen_map gather; v8-verified) ----------------
    const unsigned h  = (unsigned)bid * 256u + (unsigned)tid;   // [0, NHALO)
    const unsigned v  = h % (unsigned)NV;          // group within row
    const unsigned t2 = h / (unsigned)NV;
    const unsigned t  = t2 & 3u;                   // which halo row
    const unsigned p  = t2 >> 2;                   // plane
    const int i_out = (t < 2u) ? (int)t : (H + P + (int)t - 2);
    const int f  = (int)((p >> 6) % 6u);
    const int bC = (int)(((p >> 6) / 6u) * (6u * C) + (p & 63u));

    f32x4 val;
    #pragma unroll
    for (int e = 0; e < 4; ++e) {
        int sf, r, col;
        gen_map(f, i_out, (int)(4u * v) + e, sf, r, col);
        val[e] = x[((size_t)(bC + sf * C)) * (H * W) + ((size_t)r << 7) + col];
    }
    const size_t o = (size_t)p * (Ho * Wo) + (size_t)i_out * Wo + ((size_t)v << 2);
    __builtin_nontemporal_store(val, (f32x4*)(out + o));
}

extern "C" void kernel_launch(void* const* d_in, const int* in_sizes, int n_in,
                              void* d_out, int out_size, void* d_ws, size_t ws_size,
                              hipStream_t stream) {
    const float* x = (const float*)d_in[0];
    float* out = (float*)d_out;
    cubepad_v11_kernel<<<BLOCKS, 256, 0, stream>>>(x, out);
}